// Round 6
// baseline (230.244 us; speedup 1.0000x reference)
//
#include <hip/hip_runtime.h>
#include <hip/hip_cooperative_groups.h>

namespace cg = cooperative_groups;

#define NUM_BINS 15
#define NCOLS 200
#define BLOCK 256
#define MAXGRID 1024
#define RPI 32                 // rows per block-iteration (8 lanes/row)
#define NREP 16                // fallback path replica slots

__device__ __forceinline__ float max4(float4 q) {
    return fmaxf(fmaxf(q.x, q.y), fmaxf(q.z, q.w));
}
__device__ __forceinline__ float exp4sum(float4 q, float m) {
    return __expf(q.x - m) + __expf(q.y - m) + __expf(q.z - m) + __expf(q.w - m);
}

// Octet-per-row streaming accumulation into per-block LDS bins.
// Identical math/memory pattern to the R5 kernel (proven, no spill).
__device__ __forceinline__ void ece_block_accum(
    const float* __restrict__ logits, const int* __restrict__ targs,
    int N, int nblk,
    float* s_conf, unsigned int* s_cnt, unsigned int* s_acc)
{
    const int t = threadIdx.x;
    const int lrow = t >> 3;          // 0..31: row within block-iteration
    const int sub = t & 7;            // lane within octet
    const int stride = nblk * RPI;

    int row = blockIdx.x * RPI + lrow;
    int tg = 0;
    if (sub == 0 && row < N) tg = targs[row];   // prefetch first target idx

    for (; row < N; row += stride) {
        const float* rp = logits + (size_t)row * NCOLS + sub * 4;

        float4 q0 = *reinterpret_cast<const float4*>(rp);
        float4 q1 = *reinterpret_cast<const float4*>(rp + 32);
        float4 q2 = *reinterpret_cast<const float4*>(rp + 64);
        float4 q3 = *reinterpret_cast<const float4*>(rp + 96);
        float4 q4 = *reinterpret_cast<const float4*>(rp + 128);
        float4 q5 = *reinterpret_cast<const float4*>(rp + 160);
        const bool has7 = (sub < 2);
        float4 q6 = make_float4(-INFINITY, -INFINITY, -INFINITY, -INFINITY);
        if (has7) q6 = *reinterpret_cast<const float4*>(rp + 192);

        float tl = 0.0f;
        int tg_next = 0;
        if (sub == 0) {
            tl = logits[(size_t)row * NCOLS + tg];      // L1-hot (same row)
            int rn = row + stride;
            if (rn < N) tg_next = targs[rn];
        }

        float m = fmaxf(fmaxf(max4(q0), max4(q1)),
                        fmaxf(fmaxf(max4(q2), max4(q3)),
                              fmaxf(max4(q4), max4(q5))));
        if (has7) m = fmaxf(m, max4(q6));
        m = fmaxf(m, __shfl_xor(m, 1));
        m = fmaxf(m, __shfl_xor(m, 2));
        m = fmaxf(m, __shfl_xor(m, 4));

        float s = exp4sum(q0, m) + exp4sum(q1, m) + exp4sum(q2, m)
                + exp4sum(q3, m) + exp4sum(q4, m) + exp4sum(q5, m);
        if (has7) s += exp4sum(q6, m);
        s += __shfl_xor(s, 1);
        s += __shfl_xor(s, 2);
        s += __shfl_xor(s, 4);

        if (sub == 0) {
            float conf = 1.0f / s;                            // max softmax prob
            int b = (int)ceilf(conf * (float)NUM_BINS) - 1;   // torch (lo, hi] bins
            b = min(max(b, 0), NUM_BINS - 1);
            atomicAdd(&s_conf[b], conf);
            atomicAdd(&s_cnt[b], 1u);
            if (tl == m) atomicAdd(&s_acc[b], 1u);            // pred == targ
        }
        tg = tg_next;
    }
}

// ---------------- fused cooperative path: ONE dispatch, no memset ----------
// Per-block slots (always fully written -> poison-immune), grid.sync(),
// block 0 reduces nblk x 15 slots and writes the scalar.
__global__ __launch_bounds__(BLOCK, 4) void ece_fused_kernel(
    const float* __restrict__ logits,
    const int* __restrict__ targs,
    float* __restrict__ g_conf,       // [NUM_BINS][nblk]
    unsigned int* __restrict__ g_cnt, // [NUM_BINS][nblk]
    unsigned int* __restrict__ g_acc, // [NUM_BINS][nblk]
    float* __restrict__ out,
    int N, int nblk)
{
    __shared__ float s_conf[NUM_BINS];
    __shared__ unsigned int s_cnt[NUM_BINS];
    __shared__ unsigned int s_acc[NUM_BINS];
    __shared__ double s_term[NUM_BINS];

    const int t = threadIdx.x;
    if (t < NUM_BINS) { s_conf[t] = 0.0f; s_cnt[t] = 0u; s_acc[t] = 0u; }
    __syncthreads();

    ece_block_accum(logits, targs, N, nblk, s_conf, s_cnt, s_acc);

    __syncthreads();
    if (t < NUM_BINS) {   // agent-scope stores: visible device-wide post-sync
        __hip_atomic_store(&g_conf[t * nblk + blockIdx.x], s_conf[t],
                           __ATOMIC_RELAXED, __HIP_MEMORY_SCOPE_AGENT);
        __hip_atomic_store(&g_cnt[t * nblk + blockIdx.x], s_cnt[t],
                           __ATOMIC_RELAXED, __HIP_MEMORY_SCOPE_AGENT);
        __hip_atomic_store(&g_acc[t * nblk + blockIdx.x], s_acc[t],
                           __ATOMIC_RELAXED, __HIP_MEMORY_SCOPE_AGENT);
    }

    cg::this_grid().sync();

    if (blockIdx.x == 0) {
        // thread t = b*16 + k: 16 lanes cooperate per bin
        const int b = t >> 4, k = t & 15;
        double conf = 0.0; unsigned int cnt = 0u, acc = 0u;
        if (b < NUM_BINS) {
            for (int blk = k; blk < nblk; blk += 16) {
                conf += (double)__hip_atomic_load(&g_conf[b * nblk + blk],
                            __ATOMIC_RELAXED, __HIP_MEMORY_SCOPE_AGENT);
                cnt += __hip_atomic_load(&g_cnt[b * nblk + blk],
                            __ATOMIC_RELAXED, __HIP_MEMORY_SCOPE_AGENT);
                acc += __hip_atomic_load(&g_acc[b * nblk + blk],
                            __ATOMIC_RELAXED, __HIP_MEMORY_SCOPE_AGENT);
            }
            #pragma unroll
            for (int off = 1; off <= 8; off <<= 1) {   // stays in 16-lane group
                conf += __shfl_xor(conf, off);
                cnt  += __shfl_xor(cnt, off);
                acc  += __shfl_xor(acc, off);
            }
            if (k == 0) {
                double term = 0.0;
                if (cnt > 0u) {
                    double dc = (double)cnt;
                    term = fabs(conf / dc - (double)acc / dc) * (dc / (double)N);
                }
                s_term[b] = term;
            }
        }
        __syncthreads();
        if (t == 0) {
            double e = 0.0;
            #pragma unroll
            for (int b2 = 0; b2 < NUM_BINS; ++b2) e += s_term[b2];
            out[0] = (float)e;
        }
    }
}

// ---------------- fallback path (R5-proven): memset + main + final ---------
__global__ __launch_bounds__(BLOCK) void ece_main_kernel(
    const float* __restrict__ logits, const int* __restrict__ targs,
    double* __restrict__ g_conf, unsigned int* __restrict__ g_cnt,
    unsigned int* __restrict__ g_acc, int N, int nblk)
{
    __shared__ float s_conf[NUM_BINS];
    __shared__ unsigned int s_cnt[NUM_BINS];
    __shared__ unsigned int s_acc[NUM_BINS];
    const int t = threadIdx.x;
    if (t < NUM_BINS) { s_conf[t] = 0.0f; s_cnt[t] = 0u; s_acc[t] = 0u; }
    __syncthreads();

    ece_block_accum(logits, targs, N, nblk, s_conf, s_cnt, s_acc);

    __syncthreads();
    if (t < NUM_BINS) {
        unsigned int c = s_cnt[t];
        if (c > 0u) {
            const int rep = blockIdx.x & (NREP - 1);
            atomicAdd(&g_cnt[rep * NUM_BINS + t], c);
            atomicAdd(&g_acc[rep * NUM_BINS + t], s_acc[t]);
            atomicAdd(&g_conf[rep * NUM_BINS + t], (double)s_conf[t]);
        }
    }
}

__global__ void ece_final_kernel(
    const double* __restrict__ g_conf, const unsigned int* __restrict__ g_cnt,
    const unsigned int* __restrict__ g_acc, float* __restrict__ out, int N)
{
    const int t = threadIdx.x;
    float part = 0.0f;
    if (t < NUM_BINS) {
        double conf = 0.0;
        unsigned long long cnt = 0, acc = 0;
        #pragma unroll
        for (int r = 0; r < NREP; ++r) {
            conf += g_conf[r * NUM_BINS + t];
            cnt  += g_cnt[r * NUM_BINS + t];
            acc  += g_acc[r * NUM_BINS + t];
        }
        if (cnt > 0) {
            double dc = (double)cnt;
            part = (float)(fabs(conf / dc - (double)acc / dc) * (dc / (double)N));
        }
    }
    #pragma unroll
    for (int off = 32; off > 0; off >>= 1) part += __shfl_xor(part, off);
    if (t == 0) out[0] = part;
}

extern "C" void kernel_launch(void* const* d_in, const int* in_sizes, int n_in,
                              void* d_out, int out_size, void* d_ws, size_t ws_size,
                              hipStream_t stream) {
    const float* logits = (const float*)d_in[0];
    const int* targs = (const int*)d_in[1];   // jax int64 -> int32 on device
    int N = in_sizes[1];                      // 524288 rows
    float* out = (float*)d_out;

    // Host-side (deterministic, capture-safe) co-residency check.
    int occ = 0;
    hipError_t oe = hipOccupancyMaxActiveBlocksPerMultiprocessor(
        &occ, ece_fused_kernel, BLOCK, 0);
    int nblk = (oe == hipSuccess) ? occ * 256 : 0;       // 256 CUs on MI355X
    if (nblk > MAXGRID) nblk = MAXGRID;
    const size_t ws_need = (size_t)NUM_BINS * MAXGRID * (4 + 4 + 4);

    if (nblk >= 256 && ws_size >= ws_need) {
        // -------- fused single-dispatch cooperative path --------
        float* g_conf = (float*)d_ws;                        // [15][nblk]
        unsigned int* g_cnt = (unsigned int*)(g_conf + NUM_BINS * nblk);
        unsigned int* g_acc = g_cnt + NUM_BINS * nblk;
        void* args[] = { &logits, &targs, &g_conf, &g_cnt, &g_acc,
                         &out, &N, &nblk };
        hipLaunchCooperativeKernel((void*)ece_fused_kernel,
                                   dim3(nblk), dim3(BLOCK), args, 0, stream);
    } else {
        // -------- fallback: proven 3-dispatch path --------
        double* g_conf = (double*)d_ws;
        unsigned int* g_cnt = (unsigned int*)(g_conf + NREP * NUM_BINS);
        unsigned int* g_acc = g_cnt + NREP * NUM_BINS;
        const size_t ws_used = NREP * NUM_BINS * (sizeof(double) + 8);
        hipMemsetAsync(d_ws, 0, ws_used, stream);
        const int grid = MAXGRID;
        ece_main_kernel<<<grid, BLOCK, 0, stream>>>(logits, targs, g_conf,
                                                    g_cnt, g_acc, N, grid);
        ece_final_kernel<<<1, 64, 0, stream>>>(g_conf, g_cnt, g_acc, out, N);
    }
}

// Round 7
// 193.725 us; speedup vs baseline: 1.1885x; 1.1885x over previous
//
#include <hip/hip_runtime.h>
#include <hip/hip_cooperative_groups.h>

namespace cg = cooperative_groups;

#define NUM_BINS 15
#define NCOLS 200
#define BLOCK 256
#define MAXGRID 1024
#define RPI 32                 // rows per block-iteration (8 lanes/row)
#define NREP 16                // fallback path replica slots

__device__ __forceinline__ float max4(float4 q) {
    return fmaxf(fmaxf(q.x, q.y), fmaxf(q.z, q.w));
}
__device__ __forceinline__ float exp4sum(float4 q, float m) {
    return __expf(q.x - m) + __expf(q.y - m) + __expf(q.z - m) + __expf(q.w - m);
}

// One row's worth of per-lane data: 7 float4 (28 VGPR), statically indexed.
struct R7 { float4 a, b, c, d, e, f, g; };

__device__ __forceinline__ R7 load_row(const float* __restrict__ logits,
                                       int row, int sub, bool has7) {
    const float* rp = logits + (size_t)row * NCOLS + sub * 4;
    R7 r;
    r.a = *reinterpret_cast<const float4*>(rp);
    r.b = *reinterpret_cast<const float4*>(rp + 32);
    r.c = *reinterpret_cast<const float4*>(rp + 64);
    r.d = *reinterpret_cast<const float4*>(rp + 96);
    r.e = *reinterpret_cast<const float4*>(rp + 128);
    r.f = *reinterpret_cast<const float4*>(rp + 160);
    r.g = make_float4(-INFINITY, -INFINITY, -INFINITY, -INFINITY);
    if (has7) r.g = *reinterpret_cast<const float4*>(rp + 192);  // f4 48+sub
    return r;
}

// Row reduce + bin accumulate (octet-internal shuffles only).
__device__ __forceinline__ void compute_row(
    const R7& r, bool has7, int row, int tg, int sub,
    const float* __restrict__ logits,
    float* s_conf, unsigned int* s_cnt, unsigned int* s_acc)
{
    float tl = 0.0f;
    if (sub == 0) tl = logits[(size_t)row * NCOLS + tg];   // L1-hot (own row)

    float m = fmaxf(fmaxf(max4(r.a), max4(r.b)),
                    fmaxf(fmaxf(max4(r.c), max4(r.d)),
                          fmaxf(max4(r.e), max4(r.f))));
    if (has7) m = fmaxf(m, max4(r.g));
    m = fmaxf(m, __shfl_xor(m, 1));
    m = fmaxf(m, __shfl_xor(m, 2));
    m = fmaxf(m, __shfl_xor(m, 4));

    float s = exp4sum(r.a, m) + exp4sum(r.b, m) + exp4sum(r.c, m)
            + exp4sum(r.d, m) + exp4sum(r.e, m) + exp4sum(r.f, m);
    if (has7) s += exp4sum(r.g, m);
    s += __shfl_xor(s, 1);
    s += __shfl_xor(s, 2);
    s += __shfl_xor(s, 4);

    if (sub == 0) {
        float conf = 1.0f / s;                            // max softmax prob
        int b = (int)ceilf(conf * (float)NUM_BINS) - 1;   // torch (lo, hi] bins
        b = min(max(b, 0), NUM_BINS - 1);
        atomicAdd(&s_conf[b], conf);
        atomicAdd(&s_cnt[b], 1u);
        if (tl == m) atomicAdd(&s_acc[b], 1u);            // pred == targ
    }
}

// 2-deep software pipeline: next row's 7 independent loads are issued before
// current row's compute (ping-pong A/B register sets -> MLP is structural,
// not a scheduler choice). NO min-waves launch_bounds hint (R6 lesson:
// the ",4" hint drove VGPR to 28 and serialized all loads -> 0.8 TB/s).
__device__ __forceinline__ void ece_block_accum(
    const float* __restrict__ logits, const int* __restrict__ targs,
    int N, int nblk,
    float* s_conf, unsigned int* s_cnt, unsigned int* s_acc)
{
    const int t = threadIdx.x;
    const int lrow = t >> 3;          // 0..31: row within block-iteration
    const int sub = t & 7;            // lane within octet
    const bool has7 = (sub < 2);
    const int stride = nblk * RPI;

    int row = blockIdx.x * RPI + lrow;
    if (row >= N) return;             // uniform within octet

    int tg = (sub == 0) ? targs[row] : 0;
    R7 A = load_row(logits, row, sub, has7);
    R7 B;

    for (;;) {
        int rn = row + stride;
        bool more = rn < N;
        int tgn = 0;
        if (more) {
            B = load_row(logits, rn, sub, has7);          // issued pre-compute
            if (sub == 0) tgn = targs[rn];
        }
        compute_row(A, has7, row, tg, sub, logits, s_conf, s_cnt, s_acc);
        if (!more) break;
        row = rn; tg = tgn;

        rn = row + stride;
        more = rn < N;
        if (more) {
            A = load_row(logits, rn, sub, has7);
            if (sub == 0) tgn = targs[rn];
        }
        compute_row(B, has7, row, tg, sub, logits, s_conf, s_cnt, s_acc);
        if (!more) break;
        row = rn; tg = tgn;
    }
}

// ---------------- fused cooperative path: ONE dispatch, no memset ----------
__global__ __launch_bounds__(BLOCK) void ece_fused_kernel(
    const float* __restrict__ logits,
    const int* __restrict__ targs,
    float* __restrict__ g_conf,       // [NUM_BINS][nblk]
    unsigned int* __restrict__ g_cnt, // [NUM_BINS][nblk]
    unsigned int* __restrict__ g_acc, // [NUM_BINS][nblk]
    float* __restrict__ out,
    int N, int nblk)
{
    __shared__ float s_conf[NUM_BINS];
    __shared__ unsigned int s_cnt[NUM_BINS];
    __shared__ unsigned int s_acc[NUM_BINS];
    __shared__ double s_term[NUM_BINS];

    const int t = threadIdx.x;
    if (t < NUM_BINS) { s_conf[t] = 0.0f; s_cnt[t] = 0u; s_acc[t] = 0u; }
    __syncthreads();

    ece_block_accum(logits, targs, N, nblk, s_conf, s_cnt, s_acc);

    __syncthreads();
    if (t < NUM_BINS) {   // per-block slots, always fully written
        __hip_atomic_store(&g_conf[t * nblk + blockIdx.x], s_conf[t],
                           __ATOMIC_RELAXED, __HIP_MEMORY_SCOPE_AGENT);
        __hip_atomic_store(&g_cnt[t * nblk + blockIdx.x], s_cnt[t],
                           __ATOMIC_RELAXED, __HIP_MEMORY_SCOPE_AGENT);
        __hip_atomic_store(&g_acc[t * nblk + blockIdx.x], s_acc[t],
                           __ATOMIC_RELAXED, __HIP_MEMORY_SCOPE_AGENT);
    }

    cg::this_grid().sync();

    if (blockIdx.x == 0) {
        const int b = t >> 4, k = t & 15;   // 16 lanes cooperate per bin
        double conf = 0.0; unsigned int cnt = 0u, acc = 0u;
        if (b < NUM_BINS) {
            for (int blk = k; blk < nblk; blk += 16) {
                conf += (double)__hip_atomic_load(&g_conf[b * nblk + blk],
                            __ATOMIC_RELAXED, __HIP_MEMORY_SCOPE_AGENT);
                cnt += __hip_atomic_load(&g_cnt[b * nblk + blk],
                            __ATOMIC_RELAXED, __HIP_MEMORY_SCOPE_AGENT);
                acc += __hip_atomic_load(&g_acc[b * nblk + blk],
                            __ATOMIC_RELAXED, __HIP_MEMORY_SCOPE_AGENT);
            }
            #pragma unroll
            for (int off = 1; off <= 8; off <<= 1) {   // stays in 16-lane group
                conf += __shfl_xor(conf, off);
                cnt  += __shfl_xor(cnt, off);
                acc  += __shfl_xor(acc, off);
            }
            if (k == 0) {
                double term = 0.0;
                if (cnt > 0u) {
                    double dc = (double)cnt;
                    term = fabs(conf / dc - (double)acc / dc) * (dc / (double)N);
                }
                s_term[b] = term;
            }
        }
        __syncthreads();
        if (t == 0) {
            double e = 0.0;
            #pragma unroll
            for (int b2 = 0; b2 < NUM_BINS; ++b2) e += s_term[b2];
            out[0] = (float)e;
        }
    }
}

// ---------------- fallback path (R5-proven shape): memset + main + final ---
__global__ __launch_bounds__(BLOCK) void ece_main_kernel(
    const float* __restrict__ logits, const int* __restrict__ targs,
    double* __restrict__ g_conf, unsigned int* __restrict__ g_cnt,
    unsigned int* __restrict__ g_acc, int N, int nblk)
{
    __shared__ float s_conf[NUM_BINS];
    __shared__ unsigned int s_cnt[NUM_BINS];
    __shared__ unsigned int s_acc[NUM_BINS];
    const int t = threadIdx.x;
    if (t < NUM_BINS) { s_conf[t] = 0.0f; s_cnt[t] = 0u; s_acc[t] = 0u; }
    __syncthreads();

    ece_block_accum(logits, targs, N, nblk, s_conf, s_cnt, s_acc);

    __syncthreads();
    if (t < NUM_BINS) {
        unsigned int c = s_cnt[t];
        if (c > 0u) {
            const int rep = blockIdx.x & (NREP - 1);
            atomicAdd(&g_cnt[rep * NUM_BINS + t], c);
            atomicAdd(&g_acc[rep * NUM_BINS + t], s_acc[t]);
            atomicAdd(&g_conf[rep * NUM_BINS + t], (double)s_conf[t]);
        }
    }
}

__global__ void ece_final_kernel(
    const double* __restrict__ g_conf, const unsigned int* __restrict__ g_cnt,
    const unsigned int* __restrict__ g_acc, float* __restrict__ out, int N)
{
    const int t = threadIdx.x;
    float part = 0.0f;
    if (t < NUM_BINS) {
        double conf = 0.0;
        unsigned long long cnt = 0, acc = 0;
        #pragma unroll
        for (int r = 0; r < NREP; ++r) {
            conf += g_conf[r * NUM_BINS + t];
            cnt  += g_cnt[r * NUM_BINS + t];
            acc  += g_acc[r * NUM_BINS + t];
        }
        if (cnt > 0) {
            double dc = (double)cnt;
            part = (float)(fabs(conf / dc - (double)acc / dc) * (dc / (double)N));
        }
    }
    #pragma unroll
    for (int off = 32; off > 0; off >>= 1) part += __shfl_xor(part, off);
    if (t == 0) out[0] = part;
}

extern "C" void kernel_launch(void* const* d_in, const int* in_sizes, int n_in,
                              void* d_out, int out_size, void* d_ws, size_t ws_size,
                              hipStream_t stream) {
    const float* logits = (const float*)d_in[0];
    const int* targs = (const int*)d_in[1];   // jax int64 -> int32 on device
    int N = in_sizes[1];                      // 524288 rows
    float* out = (float*)d_out;

    // Host-side (deterministic, capture-safe) co-residency check.
    int occ = 0;
    hipError_t oe = hipOccupancyMaxActiveBlocksPerMultiprocessor(
        &occ, ece_fused_kernel, BLOCK, 0);
    int nblk = (oe == hipSuccess) ? occ * 256 : 0;       // 256 CUs on MI355X
    if (nblk > MAXGRID) nblk = MAXGRID;
    const size_t ws_need = (size_t)NUM_BINS * MAXGRID * (4 + 4 + 4);

    if (nblk >= 256 && ws_size >= ws_need) {
        // -------- fused single-dispatch cooperative path --------
        float* g_conf = (float*)d_ws;                        // [15][nblk]
        unsigned int* g_cnt = (unsigned int*)(g_conf + NUM_BINS * nblk);
        unsigned int* g_acc = g_cnt + NUM_BINS * nblk;
        void* args[] = { &logits, &targs, &g_conf, &g_cnt, &g_acc,
                         &out, &N, &nblk };
        hipLaunchCooperativeKernel((void*)ece_fused_kernel,
                                   dim3(nblk), dim3(BLOCK), args, 0, stream);
    } else {
        // -------- fallback: proven 3-dispatch path --------
        double* g_conf = (double*)d_ws;
        unsigned int* g_cnt = (unsigned int*)(g_conf + NREP * NUM_BINS);
        unsigned int* g_acc = g_cnt + NREP * NUM_BINS;
        const size_t ws_used = NREP * NUM_BINS * (sizeof(double) + 8);
        hipMemsetAsync(d_ws, 0, ws_used, stream);
        const int grid = MAXGRID;
        ece_main_kernel<<<grid, BLOCK, 0, stream>>>(logits, targs, g_conf,
                                                    g_cnt, g_acc, N, grid);
        ece_final_kernel<<<1, 64, 0, stream>>>(g_conf, g_cnt, g_acc, out, N);
    }
}

// Round 8
// 117.372 us; speedup vs baseline: 1.9617x; 1.6505x over previous
//
#include <hip/hip_runtime.h>

#define NUM_BINS 15
#define NCOLS 200
#define BLOCK 256
#define RPI 32                 // rows per block-iteration (8 lanes/row)
#define NREP 16                // fallback path replica slots

__device__ __forceinline__ float max4(float4 q) {
    return fmaxf(fmaxf(q.x, q.y), fmaxf(q.z, q.w));
}
__device__ __forceinline__ float exp4sum(float4 q, float m) {
    return __expf(q.x - m) + __expf(q.y - m) + __expf(q.z - m) + __expf(q.w - m);
}

// R5-verbatim accumulation loop (proven codegen: VGPR 84, ~5.4 TB/s), inline
// in the kernel body. Tail flush changed to per-block plain slot stores:
// every slot is written unconditionally -> no zeroing needed -> no memset
// dispatch. Visibility to the next dispatch is guaranteed by stream order.
__global__ __launch_bounds__(BLOCK) void ece_main_kernel(
    const float* __restrict__ logits,
    const int* __restrict__ targs,
    float* __restrict__ g_conf,       // [NUM_BINS][nblk] slots
    unsigned int* __restrict__ g_cnt, // [NUM_BINS][nblk]
    unsigned int* __restrict__ g_acc, // [NUM_BINS][nblk]
    int N, int nblk)
{
    __shared__ float s_conf[NUM_BINS];
    __shared__ unsigned int s_cnt[NUM_BINS];
    __shared__ unsigned int s_acc[NUM_BINS];

    const int t = threadIdx.x;
    if (t < NUM_BINS) { s_conf[t] = 0.0f; s_cnt[t] = 0u; s_acc[t] = 0u; }
    __syncthreads();

    const int lrow = t >> 3;          // 0..31: row within block-iteration
    const int sub = t & 7;            // lane within octet
    const int stride = nblk * RPI;

    int row = blockIdx.x * RPI + lrow;

    int tg = 0;
    if (sub == 0 && row < N) tg = targs[row];   // prefetch first target idx

    for (; row < N; row += stride) {
        const float* rp = logits + (size_t)row * NCOLS + sub * 4;

        float4 q0 = *reinterpret_cast<const float4*>(rp);
        float4 q1 = *reinterpret_cast<const float4*>(rp + 32);
        float4 q2 = *reinterpret_cast<const float4*>(rp + 64);
        float4 q3 = *reinterpret_cast<const float4*>(rp + 96);
        float4 q4 = *reinterpret_cast<const float4*>(rp + 128);
        float4 q5 = *reinterpret_cast<const float4*>(rp + 160);
        const bool has7 = (sub < 2);
        float4 q6 = make_float4(-INFINITY, -INFINITY, -INFINITY, -INFINITY);
        if (has7) q6 = *reinterpret_cast<const float4*>(rp + 192);

        float tl = 0.0f;
        int tg_next = 0;
        if (sub == 0) {
            tl = logits[(size_t)row * NCOLS + tg];      // L1-hot (same row)
            int rn = row + stride;
            if (rn < N) tg_next = targs[rn];
        }

        float m = fmaxf(fmaxf(max4(q0), max4(q1)),
                        fmaxf(fmaxf(max4(q2), max4(q3)),
                              fmaxf(max4(q4), max4(q5))));
        if (has7) m = fmaxf(m, max4(q6));
        m = fmaxf(m, __shfl_xor(m, 1));
        m = fmaxf(m, __shfl_xor(m, 2));
        m = fmaxf(m, __shfl_xor(m, 4));

        float s = exp4sum(q0, m) + exp4sum(q1, m) + exp4sum(q2, m)
                + exp4sum(q3, m) + exp4sum(q4, m) + exp4sum(q5, m);
        if (has7) s += exp4sum(q6, m);
        s += __shfl_xor(s, 1);
        s += __shfl_xor(s, 2);
        s += __shfl_xor(s, 4);

        if (sub == 0) {
            float conf = 1.0f / s;                            // max softmax prob
            int b = (int)ceilf(conf * (float)NUM_BINS) - 1;   // torch (lo, hi] bins
            b = min(max(b, 0), NUM_BINS - 1);
            atomicAdd(&s_conf[b], conf);
            atomicAdd(&s_cnt[b], 1u);
            if (tl == m) atomicAdd(&s_acc[b], 1u);            // pred == targ
        }
        tg = tg_next;
    }

    __syncthreads();
    if (t < NUM_BINS) {   // unconditional slot stores (poison-immune)
        g_conf[t * nblk + blockIdx.x] = s_conf[t];
        g_cnt[t * nblk + blockIdx.x] = s_cnt[t];
        g_acc[t * nblk + blockIdx.x] = s_acc[t];
    }
}

// Final reduction: 15 bins x 16 lanes each; lane k strides the nblk slots.
__global__ void ece_final_kernel(
    const float* __restrict__ g_conf,
    const unsigned int* __restrict__ g_cnt,
    const unsigned int* __restrict__ g_acc,
    float* __restrict__ out, int N, int nblk)
{
    __shared__ double s_term[NUM_BINS];
    const int t = threadIdx.x;
    if (t < 16 * NUM_BINS) {          // 240 active; 16-lane groups stay intact
        const int b = t >> 4, k = t & 15;
        double conf = 0.0;
        unsigned long long cnt = 0, acc = 0;
        for (int blk = k; blk < nblk; blk += 16) {
            conf += (double)g_conf[b * nblk + blk];
            cnt  += g_cnt[b * nblk + blk];
            acc  += g_acc[b * nblk + blk];
        }
        #pragma unroll
        for (int off = 1; off <= 8; off <<= 1) {   // within 16-lane group
            conf += __shfl_xor(conf, off);
            cnt  += __shfl_xor(cnt, off);
            acc  += __shfl_xor(acc, off);
        }
        if (k == 0) {
            double term = 0.0;
            if (cnt > 0) {
                double dc = (double)cnt;
                term = fabs(conf / dc - (double)acc / dc) * (dc / (double)N);
            }
            s_term[b] = term;
        }
    }
    __syncthreads();
    if (t == 0) {
        double e = 0.0;
        #pragma unroll
        for (int b2 = 0; b2 < NUM_BINS; ++b2) e += s_term[b2];
        out[0] = (float)e;
    }
}

// ---------------- fallback (R5-proven, needs only ~240 B ws) ---------------
__global__ __launch_bounds__(BLOCK) void ece_main_fb(
    const float* __restrict__ logits, const int* __restrict__ targs,
    double* __restrict__ g_conf, unsigned int* __restrict__ g_cnt,
    unsigned int* __restrict__ g_acc, int N, int nblk)
{
    __shared__ float s_conf[NUM_BINS];
    __shared__ unsigned int s_cnt[NUM_BINS];
    __shared__ unsigned int s_acc[NUM_BINS];
    const int t = threadIdx.x;
    if (t < NUM_BINS) { s_conf[t] = 0.0f; s_cnt[t] = 0u; s_acc[t] = 0u; }
    __syncthreads();

    const int lrow = t >> 3, sub = t & 7;
    const int stride = nblk * RPI;
    int row = blockIdx.x * RPI + lrow;
    int tg = 0;
    if (sub == 0 && row < N) tg = targs[row];

    for (; row < N; row += stride) {
        const float* rp = logits + (size_t)row * NCOLS + sub * 4;
        float4 q0 = *reinterpret_cast<const float4*>(rp);
        float4 q1 = *reinterpret_cast<const float4*>(rp + 32);
        float4 q2 = *reinterpret_cast<const float4*>(rp + 64);
        float4 q3 = *reinterpret_cast<const float4*>(rp + 96);
        float4 q4 = *reinterpret_cast<const float4*>(rp + 128);
        float4 q5 = *reinterpret_cast<const float4*>(rp + 160);
        const bool has7 = (sub < 2);
        float4 q6 = make_float4(-INFINITY, -INFINITY, -INFINITY, -INFINITY);
        if (has7) q6 = *reinterpret_cast<const float4*>(rp + 192);
        float tl = 0.0f; int tg_next = 0;
        if (sub == 0) {
            tl = logits[(size_t)row * NCOLS + tg];
            int rn = row + stride;
            if (rn < N) tg_next = targs[rn];
        }
        float m = fmaxf(fmaxf(max4(q0), max4(q1)),
                        fmaxf(fmaxf(max4(q2), max4(q3)),
                              fmaxf(max4(q4), max4(q5))));
        if (has7) m = fmaxf(m, max4(q6));
        m = fmaxf(m, __shfl_xor(m, 1));
        m = fmaxf(m, __shfl_xor(m, 2));
        m = fmaxf(m, __shfl_xor(m, 4));
        float s = exp4sum(q0, m) + exp4sum(q1, m) + exp4sum(q2, m)
                + exp4sum(q3, m) + exp4sum(q4, m) + exp4sum(q5, m);
        if (has7) s += exp4sum(q6, m);
        s += __shfl_xor(s, 1);
        s += __shfl_xor(s, 2);
        s += __shfl_xor(s, 4);
        if (sub == 0) {
            float conf = 1.0f / s;
            int b = (int)ceilf(conf * (float)NUM_BINS) - 1;
            b = min(max(b, 0), NUM_BINS - 1);
            atomicAdd(&s_conf[b], conf);
            atomicAdd(&s_cnt[b], 1u);
            if (tl == m) atomicAdd(&s_acc[b], 1u);
        }
        tg = tg_next;
    }

    __syncthreads();
    if (t < NUM_BINS) {
        unsigned int c = s_cnt[t];
        if (c > 0u) {
            const int rep = blockIdx.x & (NREP - 1);
            atomicAdd(&g_cnt[rep * NUM_BINS + t], c);
            atomicAdd(&g_acc[rep * NUM_BINS + t], s_acc[t]);
            atomicAdd(&g_conf[rep * NUM_BINS + t], (double)s_conf[t]);
        }
    }
}

__global__ void ece_final_fb(
    const double* __restrict__ g_conf, const unsigned int* __restrict__ g_cnt,
    const unsigned int* __restrict__ g_acc, float* __restrict__ out, int N)
{
    const int t = threadIdx.x;
    float part = 0.0f;
    if (t < NUM_BINS) {
        double conf = 0.0;
        unsigned long long cnt = 0, acc = 0;
        #pragma unroll
        for (int r = 0; r < NREP; ++r) {
            conf += g_conf[r * NUM_BINS + t];
            cnt  += g_cnt[r * NUM_BINS + t];
            acc  += g_acc[r * NUM_BINS + t];
        }
        if (cnt > 0) {
            double dc = (double)cnt;
            part = (float)(fabs(conf / dc - (double)acc / dc) * (dc / (double)N));
        }
    }
    #pragma unroll
    for (int off = 32; off > 0; off >>= 1) part += __shfl_xor(part, off);
    if (t == 0) out[0] = part;
}

extern "C" void kernel_launch(void* const* d_in, const int* in_sizes, int n_in,
                              void* d_out, int out_size, void* d_ws, size_t ws_size,
                              hipStream_t stream) {
    const float* logits = (const float*)d_in[0];
    const int* targs = (const int*)d_in[1];   // jax int64 -> int32 on device
    int N = in_sizes[1];                      // 524288 rows
    float* out = (float*)d_out;

    const int total_groups = (N + RPI - 1) / RPI;   // 16384

    // slot workspace: [15][nblk] x {float, u32, u32} = 12 B per slot-bin
    auto need = [](int g) { return (size_t)NUM_BINS * g * 12; };
    int nblk = 0;
    if (ws_size >= need(1536)) nblk = 1536;         // 6 blocks/CU @ 84 VGPR
    else if (ws_size >= need(1024)) nblk = 1024;
    if (nblk > total_groups) nblk = total_groups;

    if (nblk >= 256) {
        // -------- 2-dispatch slot path (no memset) --------
        float* g_conf = (float*)d_ws;
        unsigned int* g_cnt = (unsigned int*)(g_conf + NUM_BINS * nblk);
        unsigned int* g_acc = g_cnt + NUM_BINS * nblk;
        ece_main_kernel<<<nblk, BLOCK, 0, stream>>>(logits, targs, g_conf,
                                                    g_cnt, g_acc, N, nblk);
        ece_final_kernel<<<1, 256, 0, stream>>>(g_conf, g_cnt, g_acc, out,
                                                N, nblk);
    } else {
        // -------- fallback: R5-proven 3-dispatch path --------
        double* g_conf = (double*)d_ws;
        unsigned int* g_cnt = (unsigned int*)(g_conf + NREP * NUM_BINS);
        unsigned int* g_acc = g_cnt + NREP * NUM_BINS;
        const size_t ws_used = NREP * NUM_BINS * (sizeof(double) + 8);
        hipMemsetAsync(d_ws, 0, ws_used, stream);
        const int grid = 1024;
        ece_main_fb<<<grid, BLOCK, 0, stream>>>(logits, targs, g_conf,
                                                g_cnt, g_acc, N, grid);
        ece_final_fb<<<1, 64, 0, stream>>>(g_conf, g_cnt, g_acc, out, N);
    }
}

// Round 9
// 102.413 us; speedup vs baseline: 2.2482x; 1.1461x over previous
//
#include <hip/hip_runtime.h>

#define NUM_BINS 15
#define NCOLS 200
#define BLOCK 256
#define LANES_PER_ROW 8            // octet per row
#define ROWS_PER_BLOCK_ITER (BLOCK / LANES_PER_ROW)   // 32
#define GRID 1024                  // 4 blocks/CU, grid-stride persistent (compile-time!)

__device__ __forceinline__ float max4(float4 q) {
    return fmaxf(fmaxf(q.x, q.y), fmaxf(q.z, q.w));
}
__device__ __forceinline__ float exp4sum(float4 q, float m) {
    return __expf(q.x - m) + __expf(q.y - m) + __expf(q.z - m) + __expf(q.w - m);
}

// R5-verbatim main kernel (proven: VGPR 84, ~5.3 TB/s effective).
// ONLY change vs R5: the tail flush writes per-block slots unconditionally
// (instead of NREP atomicAdd) -> workspace needs no zeroing -> the memset
// dispatch is eliminated. Everything inside the row loop is byte-identical,
// and GRID stays a compile-time constant (R8 lesson: runtime nblk regressed
// codegen/locality; 117 vs 85 us).
__global__ __launch_bounds__(BLOCK) void ece_main_kernel(
    const float* __restrict__ logits,
    const int* __restrict__ targs,
    float* __restrict__ g_conf,       // [NUM_BINS][GRID] slots
    unsigned int* __restrict__ g_cnt, // [NUM_BINS][GRID]
    unsigned int* __restrict__ g_acc, // [NUM_BINS][GRID]
    int N)
{
    __shared__ float s_conf[NUM_BINS];
    __shared__ unsigned int s_cnt[NUM_BINS];
    __shared__ unsigned int s_acc[NUM_BINS];

    const int t = threadIdx.x;
    if (t < NUM_BINS) { s_conf[t] = 0.0f; s_cnt[t] = 0u; s_acc[t] = 0u; }
    __syncthreads();

    const int lrow = t >> 3;          // 0..31: row within block-iteration
    const int sub = t & 7;            // lane within octet
    const int stride = GRID * ROWS_PER_BLOCK_ITER;   // compile-time 32768

    int row = blockIdx.x * ROWS_PER_BLOCK_ITER + lrow;

    // prefetch first iteration's target index (breaks targ->logit load chain)
    int tg = 0;
    if (sub == 0 && row < N) tg = targs[row];

    for (; row < N; row += stride) {
        const float* rp = logits + (size_t)row * NCOLS + sub * 4;

        // 6 full f4 loads (f4 0..47) + 1 partial (f4 48,49 on sub<2).
        float4 q0 = *reinterpret_cast<const float4*>(rp);
        float4 q1 = *reinterpret_cast<const float4*>(rp + 32);
        float4 q2 = *reinterpret_cast<const float4*>(rp + 64);
        float4 q3 = *reinterpret_cast<const float4*>(rp + 96);
        float4 q4 = *reinterpret_cast<const float4*>(rp + 128);
        float4 q5 = *reinterpret_cast<const float4*>(rp + 160);
        const bool has7 = (sub < 2);
        float4 q6 = make_float4(-INFINITY, -INFINITY, -INFINITY, -INFINITY);
        if (has7) q6 = *reinterpret_cast<const float4*>(rp + 192);  // f4 48+sub

        // target logit for THIS row (tg prefetched) + next row's target index
        float tl = 0.0f;
        int tg_next = 0;
        if (sub == 0) {
            tl = logits[(size_t)row * NCOLS + tg];
            int rn = row + stride;
            if (rn < N) tg_next = targs[rn];
        }

        // per-lane max, then exact octet max (xor 1,2,4 stays in the octet)
        float m = fmaxf(fmaxf(max4(q0), max4(q1)),
                        fmaxf(fmaxf(max4(q2), max4(q3)),
                              fmaxf(max4(q4), max4(q5))));
        if (has7) m = fmaxf(m, max4(q6));
        m = fmaxf(m, __shfl_xor(m, 1));
        m = fmaxf(m, __shfl_xor(m, 2));
        m = fmaxf(m, __shfl_xor(m, 4));

        // sum of exp(x - rowmax)
        float s = exp4sum(q0, m) + exp4sum(q1, m) + exp4sum(q2, m)
                + exp4sum(q3, m) + exp4sum(q4, m) + exp4sum(q5, m);
        if (has7) s += exp4sum(q6, m);
        s += __shfl_xor(s, 1);
        s += __shfl_xor(s, 2);
        s += __shfl_xor(s, 4);

        if (sub == 0) {
            float conf = 1.0f / s;                            // max softmax prob
            int b = (int)ceilf(conf * (float)NUM_BINS) - 1;   // torch (lo, hi] bins
            b = min(max(b, 0), NUM_BINS - 1);
            atomicAdd(&s_conf[b], conf);
            atomicAdd(&s_cnt[b], 1u);
            if (tl == m) atomicAdd(&s_acc[b], 1u);            // pred == targ
        }
        tg = tg_next;
    }

    __syncthreads();
    if (t < NUM_BINS) {   // unconditional slot stores: poison-immune, no memset
        g_conf[t * GRID + blockIdx.x] = s_conf[t];
        g_cnt[t * GRID + blockIdx.x] = s_cnt[t];
        g_acc[t * GRID + blockIdx.x] = s_acc[t];
    }
}

// Final reduction: 15 bins x 16 lanes; lane k strides the GRID slots.
__global__ void ece_final_kernel(
    const float* __restrict__ g_conf,
    const unsigned int* __restrict__ g_cnt,
    const unsigned int* __restrict__ g_acc,
    float* __restrict__ out, int N, int nblk)
{
    __shared__ double s_term[NUM_BINS];
    const int t = threadIdx.x;
    if (t < 16 * NUM_BINS) {          // 240 active; 16-lane groups stay intact
        const int b = t >> 4, k = t & 15;
        double conf = 0.0;
        unsigned long long cnt = 0, acc = 0;
        for (int blk = k; blk < nblk; blk += 16) {
            conf += (double)g_conf[b * GRID + blk];
            cnt  += g_cnt[b * GRID + blk];
            acc  += g_acc[b * GRID + blk];
        }
        #pragma unroll
        for (int off = 1; off <= 8; off <<= 1) {   // within 16-lane group
            conf += __shfl_xor(conf, off);
            cnt  += __shfl_xor(cnt, off);
            acc  += __shfl_xor(acc, off);
        }
        if (k == 0) {
            double term = 0.0;
            if (cnt > 0) {
                double dc = (double)cnt;
                term = fabs(conf / dc - (double)acc / dc) * (dc / (double)N);
            }
            s_term[b] = term;
        }
    }
    __syncthreads();
    if (t == 0) {
        double e = 0.0;
        #pragma unroll
        for (int b2 = 0; b2 < NUM_BINS; ++b2) e += s_term[b2];
        out[0] = (float)e;
    }
}

extern "C" void kernel_launch(void* const* d_in, const int* in_sizes, int n_in,
                              void* d_out, int out_size, void* d_ws, size_t ws_size,
                              hipStream_t stream) {
    const float* logits = (const float*)d_in[0];
    const int* targs = (const int*)d_in[1];   // jax int64 -> int32 on device
    int N = in_sizes[1];                      // 524288 rows
    float* out = (float*)d_out;

    // slot workspace: [15][GRID] x {float, u32, u32} = 184320 B (ws is ~1.6 GB)
    float* g_conf = (float*)d_ws;
    unsigned int* g_cnt = (unsigned int*)(g_conf + NUM_BINS * GRID);
    unsigned int* g_acc = g_cnt + NUM_BINS * GRID;

    const int total_groups = (N + ROWS_PER_BLOCK_ITER - 1) / ROWS_PER_BLOCK_ITER;
    const int grid = min(total_groups, GRID);   // 1024 for N=524288

    // If grid < GRID, unwritten slots would hold poison -> zero them first.
    if (grid < GRID) {
        hipMemsetAsync(d_ws, 0, (size_t)NUM_BINS * GRID * 12, stream);
    }

    ece_main_kernel<<<grid, BLOCK, 0, stream>>>(logits, targs, g_conf,
                                                g_cnt, g_acc, N);
    ece_final_kernel<<<1, 256, 0, stream>>>(g_conf, g_cnt, g_acc, out,
                                            N, grid);
}

// Round 10
// 79.270 us; speedup vs baseline: 2.9046x; 1.2920x over previous
//
#include <hip/hip_runtime.h>

#define NUM_BINS 15
#define NCOLS 200
#define BLOCK 256
#define LANES_PER_ROW 8            // octet per row
#define ROWS_PER_BLOCK_ITER (BLOCK / LANES_PER_ROW)   // 32
#define GRID 1024                  // 4 blocks/CU, grid-stride persistent (compile-time!)
#define FBLOCK 1024                // final kernel: 16 waves, one per bin (15 used)

__device__ __forceinline__ float max4(float4 q) {
    return fmaxf(fmaxf(q.x, q.y), fmaxf(q.z, q.w));
}
__device__ __forceinline__ float exp4sum(float4 q, float m) {
    return __expf(q.x - m) + __expf(q.y - m) + __expf(q.z - m) + __expf(q.w - m);
}

// R5-verbatim main kernel (proven: VGPR 84, ~5.3 TB/s effective).
// Tail flush: unconditional per-block slot stores (poison-immune -> no memset
// dispatch needed when grid == GRID). Row loop untouched since R5.
__global__ __launch_bounds__(BLOCK) void ece_main_kernel(
    const float* __restrict__ logits,
    const int* __restrict__ targs,
    float* __restrict__ g_conf,       // [NUM_BINS][GRID] slots
    unsigned int* __restrict__ g_cnt, // [NUM_BINS][GRID]
    unsigned int* __restrict__ g_acc, // [NUM_BINS][GRID]
    int N)
{
    __shared__ float s_conf[NUM_BINS];
    __shared__ unsigned int s_cnt[NUM_BINS];
    __shared__ unsigned int s_acc[NUM_BINS];

    const int t = threadIdx.x;
    if (t < NUM_BINS) { s_conf[t] = 0.0f; s_cnt[t] = 0u; s_acc[t] = 0u; }
    __syncthreads();

    const int lrow = t >> 3;          // 0..31: row within block-iteration
    const int sub = t & 7;            // lane within octet
    const int stride = GRID * ROWS_PER_BLOCK_ITER;   // compile-time 32768

    int row = blockIdx.x * ROWS_PER_BLOCK_ITER + lrow;

    // prefetch first iteration's target index (breaks targ->logit load chain)
    int tg = 0;
    if (sub == 0 && row < N) tg = targs[row];

    for (; row < N; row += stride) {
        const float* rp = logits + (size_t)row * NCOLS + sub * 4;

        // 6 full f4 loads (f4 0..47) + 1 partial (f4 48,49 on sub<2).
        float4 q0 = *reinterpret_cast<const float4*>(rp);
        float4 q1 = *reinterpret_cast<const float4*>(rp + 32);
        float4 q2 = *reinterpret_cast<const float4*>(rp + 64);
        float4 q3 = *reinterpret_cast<const float4*>(rp + 96);
        float4 q4 = *reinterpret_cast<const float4*>(rp + 128);
        float4 q5 = *reinterpret_cast<const float4*>(rp + 160);
        const bool has7 = (sub < 2);
        float4 q6 = make_float4(-INFINITY, -INFINITY, -INFINITY, -INFINITY);
        if (has7) q6 = *reinterpret_cast<const float4*>(rp + 192);  // f4 48+sub

        // target logit for THIS row (tg prefetched) + next row's target index
        float tl = 0.0f;
        int tg_next = 0;
        if (sub == 0) {
            tl = logits[(size_t)row * NCOLS + tg];
            int rn = row + stride;
            if (rn < N) tg_next = targs[rn];
        }

        // per-lane max, then exact octet max (xor 1,2,4 stays in the octet)
        float m = fmaxf(fmaxf(max4(q0), max4(q1)),
                        fmaxf(fmaxf(max4(q2), max4(q3)),
                              fmaxf(max4(q4), max4(q5))));
        if (has7) m = fmaxf(m, max4(q6));
        m = fmaxf(m, __shfl_xor(m, 1));
        m = fmaxf(m, __shfl_xor(m, 2));
        m = fmaxf(m, __shfl_xor(m, 4));

        // sum of exp(x - rowmax)
        float s = exp4sum(q0, m) + exp4sum(q1, m) + exp4sum(q2, m)
                + exp4sum(q3, m) + exp4sum(q4, m) + exp4sum(q5, m);
        if (has7) s += exp4sum(q6, m);
        s += __shfl_xor(s, 1);
        s += __shfl_xor(s, 2);
        s += __shfl_xor(s, 4);

        if (sub == 0) {
            float conf = 1.0f / s;                            // max softmax prob
            int b = (int)ceilf(conf * (float)NUM_BINS) - 1;   // torch (lo, hi] bins
            b = min(max(b, 0), NUM_BINS - 1);
            atomicAdd(&s_conf[b], conf);
            atomicAdd(&s_cnt[b], 1u);
            if (tl == m) atomicAdd(&s_acc[b], 1u);            // pred == targ
        }
        tg = tg_next;
    }

    __syncthreads();
    if (t < NUM_BINS) {   // unconditional slot stores: poison-immune, no memset
        g_conf[t * GRID + blockIdx.x] = s_conf[t];
        g_cnt[t * GRID + blockIdx.x] = s_cnt[t];
        g_acc[t * GRID + blockIdx.x] = s_acc[t];
    }
}

// Final reduction, latency-parallel (R9 lesson: runtime-bound stride-16 sweep
// was ~64 serial L2/HBM latency hops ≈ 15-20 us). One wave per bin; lane k
// sums slots {k, k+64, ...}: 16 compile-time-unrolled INDEPENDENT coalesced
// loads per array -> all in flight at once; then 6-step wave reduce.
__global__ __launch_bounds__(FBLOCK) void ece_final_kernel(
    const float* __restrict__ g_conf,
    const unsigned int* __restrict__ g_cnt,
    const unsigned int* __restrict__ g_acc,
    float* __restrict__ out, int N)
{
    __shared__ double s_term[NUM_BINS];
    const int t = threadIdx.x;
    const int b = t >> 6;             // wave id = bin (15 active, wave 15 idle)
    const int k = t & 63;

    if (b < NUM_BINS) {
        double conf = 0.0;
        unsigned int cnt = 0u, acc = 0u;
        #pragma unroll
        for (int j = 0; j < GRID / 64; ++j) {      // 16 independent loads each
            const int blk = k + 64 * j;
            conf += (double)g_conf[b * GRID + blk];
            cnt  += g_cnt[b * GRID + blk];
            acc  += g_acc[b * GRID + blk];
        }
        #pragma unroll
        for (int off = 1; off <= 32; off <<= 1) {  // 64-lane reduce
            conf += __shfl_xor(conf, off);
            cnt  += __shfl_xor(cnt, off);
            acc  += __shfl_xor(acc, off);
        }
        if (k == 0) {
            double term = 0.0;
            if (cnt > 0u) {
                double dc = (double)cnt;
                term = fabs(conf / dc - (double)acc / dc) * (dc / (double)N);
            }
            s_term[b] = term;
        }
    }
    __syncthreads();
    if (t == 0) {
        double e = 0.0;
        #pragma unroll
        for (int b2 = 0; b2 < NUM_BINS; ++b2) e += s_term[b2];
        out[0] = (float)e;
    }
}

extern "C" void kernel_launch(void* const* d_in, const int* in_sizes, int n_in,
                              void* d_out, int out_size, void* d_ws, size_t ws_size,
                              hipStream_t stream) {
    const float* logits = (const float*)d_in[0];
    const int* targs = (const int*)d_in[1];   // jax int64 -> int32 on device
    int N = in_sizes[1];                      // 524288 rows
    float* out = (float*)d_out;

    // slot workspace: [15][GRID] x {float, u32, u32} = 184320 B
    float* g_conf = (float*)d_ws;
    unsigned int* g_cnt = (unsigned int*)(g_conf + NUM_BINS * GRID);
    unsigned int* g_acc = g_cnt + NUM_BINS * GRID;

    const int total_groups = (N + ROWS_PER_BLOCK_ITER - 1) / ROWS_PER_BLOCK_ITER;
    const int grid = min(total_groups, GRID);   // 1024 for N=524288

    // If grid < GRID, unwritten slots would hold poison -> zero them first.
    if (grid < GRID) {
        hipMemsetAsync(d_ws, 0, (size_t)NUM_BINS * GRID * 12, stream);
    }

    ece_main_kernel<<<grid, BLOCK, 0, stream>>>(logits, targs, g_conf,
                                                g_cnt, g_acc, N);
    ece_final_kernel<<<1, FBLOCK, 0, stream>>>(g_conf, g_cnt, g_acc, out, N);
}